// Round 4
// baseline (296.692 us; speedup 1.0000x reference)
//
#include <hip/hip_runtime.h>
#include <math.h>

#define Bn 8
#define Nn 256
#define Fn 32
#define NRBF 50
#define Hn 128
#define NK 255            // N-1 neighbors
#define ROW 8960          // N*(D+F)
#define EPSf 1e-6f
#define KP 64             // K padded 50 -> 64
#define L2E 1.44269504f

typedef __attribute__((ext_vector_type(8))) __bf16 b8;
typedef __attribute__((ext_vector_type(4))) float f32x4;

__device__ __forceinline__ float fast_sig(float z) {
    return __builtin_amdgcn_rcpf(1.f + __builtin_amdgcn_exp2f(-z * L2E));
}

// A-tile XOR swizzle: 16B chunk `ch` of row r lives at elem offset ((ch ^ (r&7))*8)
__device__ __forceinline__ int aswz(int row, int ch) {
    return row * KP + ((ch ^ (row & 7)) << 3);
}

// ---------------------------------------------------------------------------
// Prep kernel. Blocks [0,128): pack Wb[g][h][KP] bf16 (g: 0=s1_W1, 1=s1_W1*mu,
// 2=s2_W1, 3=f_W1). Blocks [128, 128+2048): per-(b,i) softmax + k-independent
// feature-half of layer 1 -> zb1/zb2/zb3 [2048][128].
// ---------------------------------------------------------------------------
__global__ __launch_bounds__(256) void prep_kernel(
    const float* __restrict__ s1_W1, const float* __restrict__ s1_b1,
    const float* __restrict__ s2_W1, const float* __restrict__ s2_b1,
    const float* __restrict__ f_W1,  const float* __restrict__ f_b1,
    const float* __restrict__ mus,   const float* __restrict__ state,
    __bf16* __restrict__ Wb,
    float* __restrict__ zb1, float* __restrict__ zb2, float* __restrict__ zb3)
{
    const int tid = threadIdx.x;
    if (blockIdx.x < 128) {
        int idx = blockIdx.x * 256 + tid;          // g*Hn*KP + h*KP + k
        int g = idx >> 13;
        int h = (idx >> 6) & 127;
        int k = idx & 63;
        float v = 0.f;
        if (k < NRBF) {
            if (g == 0)      v = s1_W1[k * Hn + h];
            else if (g == 1) v = s1_W1[k * Hn + h] * mus[k];
            else if (g == 2) v = s2_W1[k * Hn + h];
            else             v = f_W1[k * Hn + h];
        }
        Wb[idx] = (__bf16)v;
        return;
    }

    const int p = blockIdx.x - 128;                 // (b,i) pair index
    const int b = p >> 8, i = p & 255;

    __shared__ float ff[Fn], sf[Fn];
    if (tid < Fn) ff[tid] = state[b * ROW + Nn * 3 + i * Fn + tid];
    __syncthreads();
    if (tid < Fn) {
        float mx = -1e30f;
        for (int f = 0; f < Fn; f++) mx = fmaxf(mx, ff[f]);
        sf[tid] = __builtin_amdgcn_exp2f((ff[tid] - mx) * L2E);
    }
    __syncthreads();
    if (tid < Fn) {
        float s = 0.f;
        for (int f = 0; f < Fn; f++) s += sf[f];   // wave-lockstep: reads precede write
        sf[tid] = sf[tid] * __builtin_amdgcn_rcpf(s);
    }
    __syncthreads();

    const int h = tid & 127;
    if (tid < 128) {
        float z1 = s1_b1[h], z2 = s2_b1[h];
        for (int f = 0; f < Fn; f++) {
            float fv = ff[f];
            z1 += fv * (s1_W1[(NRBF + f) * Hn + h] + s1_W1[(NRBF + Fn + f) * Hn + h]);
            z2 += fv * (s2_W1[(NRBF + f) * Hn + h] + s2_W1[(NRBF + Fn + f) * Hn + h]);
        }
        zb1[p * Hn + h] = z1;
        zb2[p * Hn + h] = z2;
    } else {
        float zf = f_b1[h];
        for (int f = 0; f < Fn; f++)
            zf += sf[f] * f_W1[(NRBF + f) * Hn + h];
        zb3[p * Hn + h] = zf;
    }
}

// ---------------------------------------------------------------------------
// One block per (b,i): rbf A[256x64] bf16 in LDS (XOR-swizzled), 3 MFMA
// passes (M=64/wave, K=64), distributive fold, 3 barriers.
// ---------------------------------------------------------------------------
__global__ __launch_bounds__(256, 4) void pair_kernel(
    const float* __restrict__ state,
    const float* __restrict__ mus,   const float* __restrict__ gammap,
    const float* __restrict__ s1_W2, const float* __restrict__ s1_b2,
    const float* __restrict__ s2_W2, const float* __restrict__ s2_b2,
    const float* __restrict__ f_W2,  const float* __restrict__ f_b2,
    const __bf16* __restrict__ Wb,
    const float* __restrict__ zb1, const float* __restrict__ zb2,
    const float* __restrict__ zb3,
    float* __restrict__ vx_pre, float* __restrict__ tr_part,
    float* __restrict__ out)
{
    const int i = blockIdx.x, b = blockIdx.y;
    const int pi = b * Nn + i;
    const int tid  = threadIdx.x;
    const int w    = tid >> 6;
    const int lane = tid & 63;
    const int c    = lane & 15;       // C/D col, A m-row offset, B n
    const int q    = lane >> 4;       // quad

    __shared__ __attribute__((aligned(16))) __bf16 As[256 * KP];   // 32 KiB
    __shared__ float xpos[Nn * 3];
    __shared__ float dsh[256];
    __shared__ float musS[52];
    __shared__ float zf1s[Hn], zf2s[Hn], zffs[Hn];
    __shared__ float sW2a[Hn], sW2b[Hn];
    __shared__ float afsumsh[Hn];
    __shared__ float accum7[8];

    // ---- phase 0: stage ----
    for (int t = tid; t < Nn * 3; t += 256) xpos[t] = state[b * ROW + t];
    if (tid < NRBF) musS[tid] = mus[tid];
    if (tid < Hn) {
        zf1s[tid] = zb1[pi * Hn + tid];
        zf2s[tid] = zb2[pi * Hn + tid];
        zffs[tid] = zb3[pi * Hn + tid];
        sW2a[tid] = s1_W2[tid];
        sW2b[tid] = s2_W2[tid];
        afsumsh[tid] = 0.f;
    }
    if (tid < 8) accum7[tid] = 0.f;
    __syncthreads();                                   // S1

    const float gamma = gammap[0];

    // ---- phase 1: rbf rows -> As (bf16, swizzled) + dsh ----
    {
        const float valid = (tid < NK) ? 1.f : 0.f;
        const int   kk    = (tid < NK) ? tid : 0;
        const int   j     = kk + (kk >= i ? 1 : 0);
        float rx = (xpos[i * 3 + 0] - xpos[j * 3 + 0]) * valid;
        float ry = (xpos[i * 3 + 1] - xpos[j * 3 + 1]) * valid;
        float rz = (xpos[i * 3 + 2] - xpos[j * 3 + 2]) * valid;
        float ssq = rx * rx + ry * ry + rz * rz;
        float dd  = sqrtf(ssq + EPSf);
        dsh[tid] = dd;
        const float ngl = -gamma * L2E;
        #pragma unroll
        for (int ch = 0; ch < 8; ch++) {
            b8 v;
            #pragma unroll
            for (int jj = 0; jj < 8; jj++) {
                int m = ch * 8 + jj;
                float rv = 0.f;
                if (m < NRBF) {
                    float t = dd - musS[m];
                    rv = __builtin_amdgcn_exp2f(ngl * t * t) * valid;
                }
                v[jj] = (__bf16)rv;
            }
            *(b8*)&As[aswz(tid, ch)] = v;
        }
    }
    __syncthreads();                                   // S2

    const int row0 = w * 64;                           // wave's M-origin

    float s1p[16], ds1a[16], ds1b[16], s2p[16];
    #pragma unroll
    for (int t = 0; t < 16; t++) { s1p[t] = 0.f; ds1a[t] = 0.f; ds1b[t] = 0.f; s2p[t] = 0.f; }

    // ---- pass 1: s1 + split derivative ----
    {
        b8 a0[4], a1[4];
        #pragma unroll
        for (int mc = 0; mc < 4; mc++) {
            int rrow = row0 + mc * 16 + c;
            a0[mc] = *(const b8*)&As[aswz(rrow, q)];
            a1[mc] = *(const b8*)&As[aswz(rrow, 4 + q)];
        }
        for (int nt = 0; nt < 8; nt++) {
            int h = nt * 16 + c;
            const b8* B0 = (const b8*)&Wb[(0 * Hn + h) * KP];
            const b8* B1 = (const b8*)&Wb[(1 * Hn + h) * KP];
            b8 b00 = B0[q], b01 = B0[4 + q];
            b8 b10 = B1[q], b11 = B1[4 + q];
            float w2  = sW2a[h];
            float zf1 = zf1s[h];
            #pragma unroll
            for (int mc = 0; mc < 4; mc++) {
                f32x4 acc1 = {0.f, 0.f, 0.f, 0.f}, accm = {0.f, 0.f, 0.f, 0.f};
                acc1 = __builtin_amdgcn_mfma_f32_16x16x32_bf16(a0[mc], b00, acc1, 0, 0, 0);
                acc1 = __builtin_amdgcn_mfma_f32_16x16x32_bf16(a1[mc], b01, acc1, 0, 0, 0);
                accm = __builtin_amdgcn_mfma_f32_16x16x32_bf16(a0[mc], b10, accm, 0, 0, 0);
                accm = __builtin_amdgcn_mfma_f32_16x16x32_bf16(a1[mc], b11, accm, 0, 0, 0);
                #pragma unroll
                for (int r = 0; r < 4; r++) {
                    int idx = mc * 4 + r;
                    float zr1 = acc1[r];
                    float z1  = zr1 + zf1;
                    float sig = fast_sig(z1);
                    s1p[idx]  = fmaf(z1 * sig, w2, s1p[idx]);
                    float cc  = w2 * (sig * fmaf(z1, 1.f - sig, 1.f));  // w2*silu'(z1)
                    ds1a[idx] = fmaf(cc, zr1, ds1a[idx]);
                    ds1b[idx] = fmaf(cc, accm[r], ds1b[idx]);
                }
            }
        }
    }

    // ---- pass 2: s2 ----
    {
        b8 a0[4], a1[4];
        #pragma unroll
        for (int mc = 0; mc < 4; mc++) {
            int rrow = row0 + mc * 16 + c;
            a0[mc] = *(const b8*)&As[aswz(rrow, q)];
            a1[mc] = *(const b8*)&As[aswz(rrow, 4 + q)];
        }
        for (int nt = 0; nt < 8; nt++) {
            int h = nt * 16 + c;
            const b8* B2 = (const b8*)&Wb[(2 * Hn + h) * KP];
            b8 b20 = B2[q], b21 = B2[4 + q];
            float w2  = sW2b[h];
            float zf2 = zf2s[h];
            #pragma unroll
            for (int mc = 0; mc < 4; mc++) {
                f32x4 acc = {0.f, 0.f, 0.f, 0.f};
                acc = __builtin_amdgcn_mfma_f32_16x16x32_bf16(a0[mc], b20, acc, 0, 0, 0);
                acc = __builtin_amdgcn_mfma_f32_16x16x32_bf16(a1[mc], b21, acc, 0, 0, 0);
                #pragma unroll
                for (int r = 0; r < 4; r++) {
                    int idx = mc * 4 + r;
                    float z2  = acc[r] + zf2;
                    s2p[idx]  = fmaf(z2 * fast_sig(z2), w2, s2p[idx]);
                }
            }
        }
    }

    // ---- distributive fold: every lane folds its 16 rows; bias at c==0 ----
    {
        const float b2_1 = (c == 0) ? s1_b2[0] : 0.f;
        const float b2_2 = (c == 0) ? s2_b2[0] : 0.f;
        const float n2g  = -2.f * gamma;
        const float xi0 = xpos[i * 3 + 0], xi1 = xpos[i * 3 + 1], xi2 = xpos[i * 3 + 2];
        float p0 = 0.f, p1 = 0.f, p2 = 0.f, p3 = 0.f, p4 = 0.f, p5 = 0.f, p6 = 0.f;
        #pragma unroll
        for (int mc = 0; mc < 4; mc++)
            #pragma unroll
            for (int r = 0; r < 4; r++) {
                int idx = mc * 4 + r;
                int row = row0 + mc * 16 + q * 4 + r;
                if (row < NK) {
                    int j = row + (row >= i ? 1 : 0);
                    float rx = xi0 - xpos[j * 3 + 0];
                    float ry = xi1 - xpos[j * 3 + 1];
                    float rz = xi2 - xpos[j * 3 + 2];
                    float ssq = rx * rx + ry * ry + rz * rz;
                    float dd  = dsh[row];
                    float e1  = s1p[idx] + b2_1;
                    float e2  = s2p[idx] + b2_2;
                    float e3  = fmaf(dd, ds1a[idx], -ds1b[idx]);
                    float fr  = n2g * ssq * __builtin_amdgcn_rcpf(dd);
                    p0 = fmaf(rx, e1, p0); p1 = fmaf(ry, e1, p1); p2 = fmaf(rz, e1, p2);
                    p3 = fmaf(rx, e2, p3); p4 = fmaf(ry, e2, p4); p5 = fmaf(rz, e2, p5);
                    p6 = fmaf(fr, e3, fmaf(3.f, e1, p6));
                }
            }
        float ps[7] = {p0, p1, p2, p3, p4, p5, p6};
        #pragma unroll
        for (int off = 1; off < 64; off <<= 1)
            #pragma unroll
            for (int t = 0; t < 7; t++) ps[t] += __shfl_xor(ps[t], off, 64);
        if (lane == 0) {
            #pragma unroll
            for (int t = 0; t < 7; t++) atomicAdd(&accum7[t], ps[t]);
        }
    }

    // ---- pass 3: f MLP hidden, reduce over rows ----
    {
        b8 a0[4], a1[4];
        #pragma unroll
        for (int mc = 0; mc < 4; mc++) {
            int rrow = row0 + mc * 16 + c;
            a0[mc] = *(const b8*)&As[aswz(rrow, q)];
            a1[mc] = *(const b8*)&As[aswz(rrow, 4 + q)];
        }
        for (int nt = 0; nt < 8; nt++) {
            int h = nt * 16 + c;
            const b8* B3 = (const b8*)&Wb[(3 * Hn + h) * KP];
            b8 b30 = B3[q], b31 = B3[4 + q];
            float zff = zffs[h];
            float afp = 0.f;
            #pragma unroll
            for (int mc = 0; mc < 4; mc++) {
                f32x4 acc = {0.f, 0.f, 0.f, 0.f};
                acc = __builtin_amdgcn_mfma_f32_16x16x32_bf16(a0[mc], b30, acc, 0, 0, 0);
                acc = __builtin_amdgcn_mfma_f32_16x16x32_bf16(a1[mc], b31, acc, 0, 0, 0);
                #pragma unroll
                for (int r = 0; r < 4; r++) {
                    int row = row0 + mc * 16 + q * 4 + r;
                    float z  = acc[r] + zff;
                    float av = z * fast_sig(z);
                    afp += (row < NK) ? av : 0.f;
                }
            }
            afp += __shfl_xor(afp, 16, 64);
            afp += __shfl_xor(afp, 32, 64);
            if (lane < 16) atomicAdd(&afsumsh[h], afp);
        }
    }
    __syncthreads();                                   // S3

    if (tid == 0) {
        const float inv = 1.f / 255.f;
        float vx0 = accum7[0] * inv, vx1 = accum7[1] * inv, vx2 = accum7[2] * inv;
        float cx = (accum7[4] * vx2 - accum7[5] * vx1) * inv;
        float cy = (accum7[5] * vx0 - accum7[3] * vx2) * inv;
        float cz = (accum7[3] * vx1 - accum7[4] * vx0) * inv;
        vx_pre[pi * 4 + 0] = vx0 + cx;
        vx_pre[pi * 4 + 1] = vx1 + cy;
        vx_pre[pi * 4 + 2] = vx2 + cz;
        tr_part[pi] = accum7[6];
    }

    if (tid < Fn) {
        float acc = 0.f;
        for (int h = 0; h < Hn; h++) acc = fmaf(afsumsh[h], f_W2[h * Fn + tid], acc);
        out[b * ROW + Nn * 3 + i * Fn + tid] = fmaf(acc, 1.f / 255.f, f_b2[tid]);
    }
}

// ---------------------------------------------------------------------------
__global__ __launch_bounds__(256) void finalize_kernel(
    const float* __restrict__ vx_pre, const float* __restrict__ tr_part,
    float* __restrict__ out)
{
    int b = blockIdx.x, tid = threadIdx.x;
    int bi = b * Nn + tid;
    float v0 = vx_pre[bi * 4 + 0];
    float v1 = vx_pre[bi * 4 + 1];
    float v2 = vx_pre[bi * 4 + 2];
    float tr = tr_part[bi];

    __shared__ float red[4][4];
    __shared__ float fin[4];
    float vals[4] = {v0, v1, v2, tr};
    #pragma unroll
    for (int cc = 0; cc < 4; cc++) {
        float v = vals[cc];
        #pragma unroll
        for (int off = 32; off; off >>= 1) v += __shfl_down(v, off, 64);
        if ((tid & 63) == 0) red[tid >> 6][cc] = v;
    }
    __syncthreads();
    if (tid < 4) fin[tid] = red[0][tid] + red[1][tid] + red[2][tid] + red[3][tid];
    __syncthreads();

    out[b * ROW + tid * 3 + 0] = v0 - fin[0] * (1.f / 256.f);
    out[b * ROW + tid * 3 + 1] = v1 - fin[1] * (1.f / 256.f);
    out[b * ROW + tid * 3 + 2] = v2 - fin[2] * (1.f / 256.f);
    if (tid == 0) out[Bn * ROW + b] = fin[3] * (1.f / 255.f);
}

// ---------------------------------------------------------------------------
extern "C" void kernel_launch(void* const* d_in, const int* in_sizes, int n_in,
                              void* d_out, int out_size, void* d_ws, size_t ws_size,
                              hipStream_t stream)
{
    const float* state = (const float*)d_in[1];
    const float* mus   = (const float*)d_in[2];
    const float* gam   = (const float*)d_in[3];
    const float* s1_W1 = (const float*)d_in[4];
    const float* s1_b1 = (const float*)d_in[5];
    const float* s1_W2 = (const float*)d_in[6];
    const float* s1_b2 = (const float*)d_in[7];
    const float* s2_W1 = (const float*)d_in[8];
    const float* s2_b1 = (const float*)d_in[9];
    const float* s2_W2 = (const float*)d_in[10];
    const float* s2_b2 = (const float*)d_in[11];
    const float* f_W1  = (const float*)d_in[12];
    const float* f_b1  = (const float*)d_in[13];
    const float* f_W2  = (const float*)d_in[14];
    const float* f_b2  = (const float*)d_in[15];

    char* wsb = (char*)d_ws;
    __bf16* Wb   = (__bf16*)wsb;                       // 65,536 B
    float* zb1   = (float*)(wsb + 65536);              // 1 MiB
    float* zb2   = zb1 + Bn * Nn * Hn;
    float* zb3   = zb2 + Bn * Nn * Hn;
    float* vx_pre  = zb3 + Bn * Nn * Hn;
    float* tr_part = vx_pre + Bn * Nn * 4;
    float* out   = (float*)d_out;

    prep_kernel<<<128 + Bn * Nn, 256, 0, stream>>>(
        s1_W1, s1_b1, s2_W1, s2_b1, f_W1, f_b1, mus, state, Wb, zb1, zb2, zb3);

    dim3 grid(Nn, Bn);
    pair_kernel<<<grid, 256, 0, stream>>>(state, mus, gam,
        s1_W2, s1_b2, s2_W2, s2_b2, f_W2, f_b2,
        Wb, zb1, zb2, zb3, vx_pre, tr_part, out);

    finalize_kernel<<<Bn, 256, 0, stream>>>(vx_pre, tr_part, out);
}

// Round 5
// 203.040 us; speedup vs baseline: 1.4613x; 1.4613x over previous
//
#include <hip/hip_runtime.h>
#include <math.h>

#define Bn 8
#define Nn 256
#define Fn 32
#define NRBF 50
#define Hn 128
#define NK 255            // N-1 neighbors
#define ROW 8960          // N*(D+F)
#define EPSf 1e-6f
#define KP 64             // K padded 50 -> 64
#define L2E 1.44269504f

typedef __attribute__((ext_vector_type(8))) __bf16 b8;
typedef __attribute__((ext_vector_type(4))) float f32x4;

__device__ __forceinline__ float fast_sig(float z) {
    return __builtin_amdgcn_rcpf(1.f + __builtin_amdgcn_exp2f(-z * L2E));
}

// A-tile XOR swizzle: 16B chunk `ch` of row r lives at elem offset ((ch ^ (r&7))*8)
__device__ __forceinline__ int aswz(int row, int ch) {
    return row * KP + ((ch ^ (row & 7)) << 3);
}

// ---------------------------------------------------------------------------
// Prep kernel. Blocks [0,128): pack Wb[g][h][KP] bf16 (g: 0=s1_W1, 1=s1_W1*mu,
// 2=s2_W1, 3=f_W1). Blocks [128, 128+2048): per-(b,i) softmax + k-independent
// feature-half of layer 1 -> zb1/zb2/zb3 [2048][128].
// ---------------------------------------------------------------------------
__global__ __launch_bounds__(256) void prep_kernel(
    const float* __restrict__ s1_W1, const float* __restrict__ s1_b1,
    const float* __restrict__ s2_W1, const float* __restrict__ s2_b1,
    const float* __restrict__ f_W1,  const float* __restrict__ f_b1,
    const float* __restrict__ mus,   const float* __restrict__ state,
    __bf16* __restrict__ Wb,
    float* __restrict__ zb1, float* __restrict__ zb2, float* __restrict__ zb3)
{
    const int tid = threadIdx.x;
    if (blockIdx.x < 128) {
        int idx = blockIdx.x * 256 + tid;          // g*Hn*KP + h*KP + k
        int g = idx >> 13;
        int h = (idx >> 6) & 127;
        int k = idx & 63;
        float v = 0.f;
        if (k < NRBF) {
            if (g == 0)      v = s1_W1[k * Hn + h];
            else if (g == 1) v = s1_W1[k * Hn + h] * mus[k];
            else if (g == 2) v = s2_W1[k * Hn + h];
            else             v = f_W1[k * Hn + h];
        }
        Wb[idx] = (__bf16)v;
        return;
    }

    const int p = blockIdx.x - 128;                 // (b,i) pair index
    const int b = p >> 8, i = p & 255;

    __shared__ float ff[Fn], sf[Fn];
    if (tid < Fn) ff[tid] = state[b * ROW + Nn * 3 + i * Fn + tid];
    __syncthreads();
    if (tid < Fn) {
        float mx = -1e30f;
        for (int f = 0; f < Fn; f++) mx = fmaxf(mx, ff[f]);
        sf[tid] = __builtin_amdgcn_exp2f((ff[tid] - mx) * L2E);
    }
    __syncthreads();
    if (tid < Fn) {
        float s = 0.f;
        for (int f = 0; f < Fn; f++) s += sf[f];   // wave-lockstep: reads precede write
        sf[tid] = sf[tid] * __builtin_amdgcn_rcpf(s);
    }
    __syncthreads();

    const int h = tid & 127;
    if (tid < 128) {
        float z1 = s1_b1[h], z2 = s2_b1[h];
        for (int f = 0; f < Fn; f++) {
            float fv = ff[f];
            z1 += fv * (s1_W1[(NRBF + f) * Hn + h] + s1_W1[(NRBF + Fn + f) * Hn + h]);
            z2 += fv * (s2_W1[(NRBF + f) * Hn + h] + s2_W1[(NRBF + Fn + f) * Hn + h]);
        }
        zb1[p * Hn + h] = z1;
        zb2[p * Hn + h] = z2;
    } else {
        float zf = f_b1[h];
        for (int f = 0; f < Fn; f++)
            zf += sf[f] * f_W1[(NRBF + f) * Hn + h];
        zb3[p * Hn + h] = zf;
    }
}

// ---------------------------------------------------------------------------
// One block per (b,i): rbf A[256x64] bf16 in LDS (XOR-swizzled), 3 MFMA
// passes (M=64/wave, K=64), distributive fold, 3 barriers.
// __launch_bounds__(256,2): R4's (256,4) forced 64 VGPRs -> 500 MB scratch
// spill traffic (FETCH 232 MB, WRITE 280 MB). 128 VGPR + <40 KB LDS still
// admits 4 blocks/CU in hardware.
// ---------------------------------------------------------------------------
__global__ __launch_bounds__(256, 2) void pair_kernel(
    const float* __restrict__ state,
    const float* __restrict__ mus,   const float* __restrict__ gammap,
    const float* __restrict__ s1_W2, const float* __restrict__ s1_b2,
    const float* __restrict__ s2_W2, const float* __restrict__ s2_b2,
    const float* __restrict__ f_W2,  const float* __restrict__ f_b2,
    const __bf16* __restrict__ Wb,
    const float* __restrict__ zb1, const float* __restrict__ zb2,
    const float* __restrict__ zb3,
    float* __restrict__ vx_pre, float* __restrict__ tr_part,
    float* __restrict__ out)
{
    const int i = blockIdx.x, b = blockIdx.y;
    const int pi = b * Nn + i;
    const int tid  = threadIdx.x;
    const int w    = tid >> 6;
    const int lane = tid & 63;
    const int c    = lane & 15;       // C/D col, A m-row offset, B n
    const int q    = lane >> 4;       // quad

    __shared__ __attribute__((aligned(16))) __bf16 As[256 * KP];   // 32 KiB
    __shared__ float xpos[Nn * 3];
    __shared__ float musS[52];
    __shared__ float zf1s[Hn], zf2s[Hn], zffs[Hn];
    __shared__ float sW2a[Hn], sW2b[Hn];
    __shared__ float afsumsh[Hn];
    __shared__ float accum7[8];

    // ---- phase 0: stage ----
    for (int t = tid; t < Nn * 3; t += 256) xpos[t] = state[b * ROW + t];
    if (tid < NRBF) musS[tid] = mus[tid];
    if (tid < Hn) {
        zf1s[tid] = zb1[pi * Hn + tid];
        zf2s[tid] = zb2[pi * Hn + tid];
        zffs[tid] = zb3[pi * Hn + tid];
        sW2a[tid] = s1_W2[tid];
        sW2b[tid] = s2_W2[tid];
        afsumsh[tid] = 0.f;
    }
    if (tid < 8) accum7[tid] = 0.f;
    __syncthreads();                                   // S1

    const float gamma = gammap[0];

    // ---- phase 1: rbf rows -> As (bf16, swizzled) ----
    {
        const float valid = (tid < NK) ? 1.f : 0.f;
        const int   kk    = (tid < NK) ? tid : 0;
        const int   j     = kk + (kk >= i ? 1 : 0);
        float rx = (xpos[i * 3 + 0] - xpos[j * 3 + 0]) * valid;
        float ry = (xpos[i * 3 + 1] - xpos[j * 3 + 1]) * valid;
        float rz = (xpos[i * 3 + 2] - xpos[j * 3 + 2]) * valid;
        float ssq = rx * rx + ry * ry + rz * rz;
        float dd  = sqrtf(ssq + EPSf);
        const float ngl = -gamma * L2E;
        #pragma unroll
        for (int ch = 0; ch < 8; ch++) {
            b8 v;
            #pragma unroll
            for (int jj = 0; jj < 8; jj++) {
                int m = ch * 8 + jj;
                float rv = 0.f;
                if (m < NRBF) {
                    float t = dd - musS[m];
                    rv = __builtin_amdgcn_exp2f(ngl * t * t) * valid;
                }
                v[jj] = (__bf16)rv;
            }
            *(b8*)&As[aswz(tid, ch)] = v;
        }
    }
    __syncthreads();                                   // S2

    const int row0 = w * 64;                           // wave's M-origin

    float s1p[16], ds1a[16], ds1b[16], s2p[16];
    #pragma unroll
    for (int t = 0; t < 16; t++) { s1p[t] = 0.f; ds1a[t] = 0.f; ds1b[t] = 0.f; s2p[t] = 0.f; }

    // ---- pass 1: s1 + split derivative ----
    {
        b8 a0[4], a1[4];
        #pragma unroll
        for (int mc = 0; mc < 4; mc++) {
            int rrow = row0 + mc * 16 + c;
            a0[mc] = *(const b8*)&As[aswz(rrow, q)];
            a1[mc] = *(const b8*)&As[aswz(rrow, 4 + q)];
        }
        for (int nt = 0; nt < 8; nt++) {
            int h = nt * 16 + c;
            const b8* B0 = (const b8*)&Wb[(0 * Hn + h) * KP];
            const b8* B1 = (const b8*)&Wb[(1 * Hn + h) * KP];
            b8 b00 = B0[q], b01 = B0[4 + q];
            b8 b10 = B1[q], b11 = B1[4 + q];
            float w2  = sW2a[h];
            float zf1 = zf1s[h];
            #pragma unroll
            for (int mc = 0; mc < 4; mc++) {
                f32x4 acc1 = {0.f, 0.f, 0.f, 0.f}, accm = {0.f, 0.f, 0.f, 0.f};
                acc1 = __builtin_amdgcn_mfma_f32_16x16x32_bf16(a0[mc], b00, acc1, 0, 0, 0);
                acc1 = __builtin_amdgcn_mfma_f32_16x16x32_bf16(a1[mc], b01, acc1, 0, 0, 0);
                accm = __builtin_amdgcn_mfma_f32_16x16x32_bf16(a0[mc], b10, accm, 0, 0, 0);
                accm = __builtin_amdgcn_mfma_f32_16x16x32_bf16(a1[mc], b11, accm, 0, 0, 0);
                #pragma unroll
                for (int r = 0; r < 4; r++) {
                    int idx = mc * 4 + r;
                    float zr1 = acc1[r];
                    float z1  = zr1 + zf1;
                    float sig = fast_sig(z1);
                    s1p[idx]  = fmaf(z1 * sig, w2, s1p[idx]);
                    float cc  = w2 * (sig * fmaf(z1, 1.f - sig, 1.f));  // w2*silu'(z1)
                    ds1a[idx] = fmaf(cc, zr1, ds1a[idx]);
                    ds1b[idx] = fmaf(cc, accm[r], ds1b[idx]);
                }
            }
        }
    }

    // ---- pass 2: s2 ----
    {
        b8 a0[4], a1[4];
        #pragma unroll
        for (int mc = 0; mc < 4; mc++) {
            int rrow = row0 + mc * 16 + c;
            a0[mc] = *(const b8*)&As[aswz(rrow, q)];
            a1[mc] = *(const b8*)&As[aswz(rrow, 4 + q)];
        }
        for (int nt = 0; nt < 8; nt++) {
            int h = nt * 16 + c;
            const b8* B2 = (const b8*)&Wb[(2 * Hn + h) * KP];
            b8 b20 = B2[q], b21 = B2[4 + q];
            float w2  = sW2b[h];
            float zf2 = zf2s[h];
            #pragma unroll
            for (int mc = 0; mc < 4; mc++) {
                f32x4 acc = {0.f, 0.f, 0.f, 0.f};
                acc = __builtin_amdgcn_mfma_f32_16x16x32_bf16(a0[mc], b20, acc, 0, 0, 0);
                acc = __builtin_amdgcn_mfma_f32_16x16x32_bf16(a1[mc], b21, acc, 0, 0, 0);
                #pragma unroll
                for (int r = 0; r < 4; r++) {
                    int idx = mc * 4 + r;
                    float z2  = acc[r] + zf2;
                    s2p[idx]  = fmaf(z2 * fast_sig(z2), w2, s2p[idx]);
                }
            }
        }
    }

    // ---- distributive fold: every lane folds its 16 rows; bias at c==0 ----
    {
        const float b2_1 = (c == 0) ? s1_b2[0] : 0.f;
        const float b2_2 = (c == 0) ? s2_b2[0] : 0.f;
        const float n2g  = -2.f * gamma;
        const float xi0 = xpos[i * 3 + 0], xi1 = xpos[i * 3 + 1], xi2 = xpos[i * 3 + 2];
        float p0 = 0.f, p1 = 0.f, p2 = 0.f, p3 = 0.f, p4 = 0.f, p5 = 0.f, p6 = 0.f;
        #pragma unroll
        for (int mc = 0; mc < 4; mc++)
            #pragma unroll
            for (int r = 0; r < 4; r++) {
                int idx = mc * 4 + r;
                int row = row0 + mc * 16 + q * 4 + r;
                if (row < NK) {
                    int j = row + (row >= i ? 1 : 0);
                    float rx = xi0 - xpos[j * 3 + 0];
                    float ry = xi1 - xpos[j * 3 + 1];
                    float rz = xi2 - xpos[j * 3 + 2];
                    float ssq = rx * rx + ry * ry + rz * rz;
                    float dd  = sqrtf(ssq + EPSf);
                    float e1  = s1p[idx] + b2_1;
                    float e2  = s2p[idx] + b2_2;
                    float e3  = fmaf(dd, ds1a[idx], -ds1b[idx]);
                    float fr  = n2g * ssq * __builtin_amdgcn_rcpf(dd);
                    p0 = fmaf(rx, e1, p0); p1 = fmaf(ry, e1, p1); p2 = fmaf(rz, e1, p2);
                    p3 = fmaf(rx, e2, p3); p4 = fmaf(ry, e2, p4); p5 = fmaf(rz, e2, p5);
                    p6 = fmaf(fr, e3, fmaf(3.f, e1, p6));
                }
            }
        float ps[7] = {p0, p1, p2, p3, p4, p5, p6};
        #pragma unroll
        for (int off = 1; off < 64; off <<= 1)
            #pragma unroll
            for (int t = 0; t < 7; t++) ps[t] += __shfl_xor(ps[t], off, 64);
        if (lane == 0) {
            #pragma unroll
            for (int t = 0; t < 7; t++) atomicAdd(&accum7[t], ps[t]);
        }
    }

    // ---- pass 3: f MLP hidden, reduce over rows ----
    {
        b8 a0[4], a1[4];
        #pragma unroll
        for (int mc = 0; mc < 4; mc++) {
            int rrow = row0 + mc * 16 + c;
            a0[mc] = *(const b8*)&As[aswz(rrow, q)];
            a1[mc] = *(const b8*)&As[aswz(rrow, 4 + q)];
        }
        for (int nt = 0; nt < 8; nt++) {
            int h = nt * 16 + c;
            const b8* B3 = (const b8*)&Wb[(3 * Hn + h) * KP];
            b8 b30 = B3[q], b31 = B3[4 + q];
            float zff = zffs[h];
            float afp = 0.f;
            #pragma unroll
            for (int mc = 0; mc < 4; mc++) {
                f32x4 acc = {0.f, 0.f, 0.f, 0.f};
                acc = __builtin_amdgcn_mfma_f32_16x16x32_bf16(a0[mc], b30, acc, 0, 0, 0);
                acc = __builtin_amdgcn_mfma_f32_16x16x32_bf16(a1[mc], b31, acc, 0, 0, 0);
                #pragma unroll
                for (int r = 0; r < 4; r++) {
                    int row = row0 + mc * 16 + q * 4 + r;
                    float z  = acc[r] + zff;
                    float av = z * fast_sig(z);
                    afp += (row < NK) ? av : 0.f;
                }
            }
            afp += __shfl_xor(afp, 16, 64);
            afp += __shfl_xor(afp, 32, 64);
            if (lane < 16) atomicAdd(&afsumsh[h], afp);
        }
    }
    __syncthreads();                                   // S3

    if (tid == 0) {
        const float inv = 1.f / 255.f;
        float vx0 = accum7[0] * inv, vx1 = accum7[1] * inv, vx2 = accum7[2] * inv;
        float cx = (accum7[4] * vx2 - accum7[5] * vx1) * inv;
        float cy = (accum7[5] * vx0 - accum7[3] * vx2) * inv;
        float cz = (accum7[3] * vx1 - accum7[4] * vx0) * inv;
        vx_pre[pi * 4 + 0] = vx0 + cx;
        vx_pre[pi * 4 + 1] = vx1 + cy;
        vx_pre[pi * 4 + 2] = vx2 + cz;
        tr_part[pi] = accum7[6];
    }

    if (tid < Fn) {
        float acc = 0.f;
        for (int h = 0; h < Hn; h++) acc = fmaf(afsumsh[h], f_W2[h * Fn + tid], acc);
        out[b * ROW + Nn * 3 + i * Fn + tid] = fmaf(acc, 1.f / 255.f, f_b2[tid]);
    }
}

// ---------------------------------------------------------------------------
__global__ __launch_bounds__(256) void finalize_kernel(
    const float* __restrict__ vx_pre, const float* __restrict__ tr_part,
    float* __restrict__ out)
{
    int b = blockIdx.x, tid = threadIdx.x;
    int bi = b * Nn + tid;
    float v0 = vx_pre[bi * 4 + 0];
    float v1 = vx_pre[bi * 4 + 1];
    float v2 = vx_pre[bi * 4 + 2];
    float tr = tr_part[bi];

    __shared__ float red[4][4];
    __shared__ float fin[4];
    float vals[4] = {v0, v1, v2, tr};
    #pragma unroll
    for (int cc = 0; cc < 4; cc++) {
        float v = vals[cc];
        #pragma unroll
        for (int off = 32; off; off >>= 1) v += __shfl_down(v, off, 64);
        if ((tid & 63) == 0) red[tid >> 6][cc] = v;
    }
    __syncthreads();
    if (tid < 4) fin[tid] = red[0][tid] + red[1][tid] + red[2][tid] + red[3][tid];
    __syncthreads();

    out[b * ROW + tid * 3 + 0] = v0 - fin[0] * (1.f / 256.f);
    out[b * ROW + tid * 3 + 1] = v1 - fin[1] * (1.f / 256.f);
    out[b * ROW + tid * 3 + 2] = v2 - fin[2] * (1.f / 256.f);
    if (tid == 0) out[Bn * ROW + b] = fin[3] * (1.f / 255.f);
}

// ---------------------------------------------------------------------------
extern "C" void kernel_launch(void* const* d_in, const int* in_sizes, int n_in,
                              void* d_out, int out_size, void* d_ws, size_t ws_size,
                              hipStream_t stream)
{
    const float* state = (const float*)d_in[1];
    const float* mus   = (const float*)d_in[2];
    const float* gam   = (const float*)d_in[3];
    const float* s1_W1 = (const float*)d_in[4];
    const float* s1_b1 = (const float*)d_in[5];
    const float* s1_W2 = (const float*)d_in[6];
    const float* s1_b2 = (const float*)d_in[7];
    const float* s2_W1 = (const float*)d_in[8];
    const float* s2_b1 = (const float*)d_in[9];
    const float* s2_W2 = (const float*)d_in[10];
    const float* s2_b2 = (const float*)d_in[11];
    const float* f_W1  = (const float*)d_in[12];
    const float* f_b1  = (const float*)d_in[13];
    const float* f_W2  = (const float*)d_in[14];
    const float* f_b2  = (const float*)d_in[15];

    char* wsb = (char*)d_ws;
    __bf16* Wb   = (__bf16*)wsb;                       // 65,536 B
    float* zb1   = (float*)(wsb + 65536);              // 1 MiB each
    float* zb2   = zb1 + Bn * Nn * Hn;
    float* zb3   = zb2 + Bn * Nn * Hn;
    float* vx_pre  = zb3 + Bn * Nn * Hn;
    float* tr_part = vx_pre + Bn * Nn * 4;
    float* out   = (float*)d_out;

    prep_kernel<<<128 + Bn * Nn, 256, 0, stream>>>(
        s1_W1, s1_b1, s2_W1, s2_b1, f_W1, f_b1, mus, state, Wb, zb1, zb2, zb3);

    dim3 grid(Nn, Bn);
    pair_kernel<<<grid, 256, 0, stream>>>(state, mus, gam,
        s1_W2, s1_b2, s2_W2, s2_b2, f_W2, f_b2,
        Wb, zb1, zb2, zb3, vx_pre, tr_part, out);

    finalize_kernel<<<Bn, 256, 0, stream>>>(vx_pre, tr_part, out);
}